// Round 1
// baseline (3716.418 us; speedup 1.0000x reference)
//
#include <hip/hip_runtime.h>
#include <math.h>

#define NSLOTS 4096
#define DIM    128
#define HDIM   1024
#define NTOK   16384   // 4 * 4096
#define SCALE  0.08838834764831845f  // 1/sqrt(128)
#define REPS   1e-10f

// ---------------- kernel 0: log-reliability precompute ----------------
__global__ void lr_kernel(const float* __restrict__ rel, float* __restrict__ lr) {
    int j = blockIdx.x * 256 + threadIdx.x;
    if (j < NSLOTS) lr[j] = logf(rel[j] + REPS);
}

// ---------------- kernel 1: fused router GEMM + top-8 + softmax ----------------
// Block: 256 threads = 16 tokens x 16 threads-per-token.
// Each thread scans 256 slots (stride 16, 4 slots per outer iter), keeping a
// sorted (ascending) top-8 of biased scores in registers. Merge: 16-lane
// shuffle-butterfly pop-merge (stable: ties -> lower slot index, matching
// jax.lax.top_k). Lane r==0 computes softmax on the *unbiased* scores.

#define CSWAP(x, y, ix, iy) \
    { if (x > y) { float tf = x; x = y; y = tf; int ti = ix; ix = iy; iy = ti; } }

#define INSERT(sc, jj)                                              \
    if (sc > s0) {                                                  \
        s0 = sc; i0 = jj;                                           \
        CSWAP(s0, s1, i0, i1); CSWAP(s1, s2, i1, i2);               \
        CSWAP(s2, s3, i2, i3); CSWAP(s3, s4, i3, i4);               \
        CSWAP(s4, s5, i4, i5); CSWAP(s5, s6, i5, i6);               \
        CSWAP(s6, s7, i6, i7);                                      \
    }

__launch_bounds__(256)
__global__ void route_kernel(const float* __restrict__ query,
                             const float* __restrict__ keys,
                             const float* __restrict__ lr,
                             float* __restrict__ wout,   // attn_weights out
                             int*   __restrict__ idxws,
                             float* __restrict__ wws) {
    __shared__ float qs[16 * 132];   // 16 tokens x 128 dims, padded +4 floats
    const int tid  = threadIdx.x;
    const int tok0 = blockIdx.x * 16;

    // cooperative coalesced Q load (16 x 128 floats = 512 float4)
    const float4* qsrc = (const float4*)(query + (size_t)tok0 * DIM);
    for (int v = tid; v < 16 * 32; v += 256) {
        int t = v >> 5, d4 = v & 31;
        float4 val = qsrc[t * 32 + d4];
        float* dst = &qs[t * 132 + d4 * 4];
        dst[0] = val.x; dst[1] = val.y; dst[2] = val.z; dst[3] = val.w;
    }
    __syncthreads();

    const int t = tid >> 4;   // token within block (0..15)
    const int r = tid & 15;   // slot residue     (0..15)
    const float4* q4 = (const float4*)(qs + t * 132);
    const float4* K4 = (const float4*)keys;

    float s0 = -INFINITY, s1 = -INFINITY, s2 = -INFINITY, s3 = -INFINITY,
          s4 = -INFINITY, s5 = -INFINITY, s6 = -INFINITY, s7 = -INFINITY;
    int   i0 = 0x7fffffff, i1 = 0x7fffffff, i2 = 0x7fffffff, i3 = 0x7fffffff,
          i4 = 0x7fffffff, i5 = 0x7fffffff, i6 = 0x7fffffff, i7 = 0x7fffffff;

    for (int it = 0; it < 64; ++it) {
        const int j0 = r + (it << 6);
        const float4* k0p = K4 + (size_t)j0 * 32;
        const float4* k1p = k0p + 16 * 32;
        const float4* k2p = k0p + 32 * 32;
        const float4* k3p = k0p + 48 * 32;

        float a0 = 0.f, b0 = 0.f, a1 = 0.f, b1 = 0.f;
        float a2 = 0.f, b2 = 0.f, a3 = 0.f, b3 = 0.f;
        #pragma unroll 8
        for (int d = 0; d < 32; ++d) {
            float4 qv = q4[d];
            float4 k0 = k0p[d];
            float4 k1 = k1p[d];
            float4 k2 = k2p[d];
            float4 k3 = k3p[d];
            a0 = fmaf(qv.x, k0.x, a0); b0 = fmaf(qv.y, k0.y, b0);
            a0 = fmaf(qv.z, k0.z, a0); b0 = fmaf(qv.w, k0.w, b0);
            a1 = fmaf(qv.x, k1.x, a1); b1 = fmaf(qv.y, k1.y, b1);
            a1 = fmaf(qv.z, k1.z, a1); b1 = fmaf(qv.w, k1.w, b1);
            a2 = fmaf(qv.x, k2.x, a2); b2 = fmaf(qv.y, k2.y, b2);
            a2 = fmaf(qv.z, k2.z, a2); b2 = fmaf(qv.w, k2.w, b2);
            a3 = fmaf(qv.x, k3.x, a3); b3 = fmaf(qv.y, k3.y, b3);
            a3 = fmaf(qv.z, k3.z, a3); b3 = fmaf(qv.w, k3.w, b3);
        }
        float sc0 = (a0 + b0) + lr[j0];
        float sc1 = (a1 + b1) + lr[j0 + 16];
        float sc2 = (a2 + b2) + lr[j0 + 32];
        float sc3 = (a3 + b3) + lr[j0 + 48];
        INSERT(sc0, j0);
        INSERT(sc1, j0 + 16);
        INSERT(sc2, j0 + 32);
        INSERT(sc3, j0 + 48);
    }

    // ---- stable pop-merge across the 16 lanes of this token ----
    float hv = s7; int hi = i7;   // current head (each thread's max)
    float topv[8]; int topi[8];
    #pragma unroll
    for (int round = 0; round < 8; ++round) {
        float bv = hv; int bi = hi;
        #pragma unroll
        for (int off = 1; off < 16; off <<= 1) {
            float ov = __shfl_xor(bv, off, 16);
            int   oi = __shfl_xor(bi, off, 16);
            if (ov > bv || (ov == bv && oi < bi)) { bv = ov; bi = oi; }
        }
        topv[round] = bv; topi[round] = bi;
        bool win = (hv == bv) && (hi == bi);
        if (win) {  // pop my head: shift sorted array up
            s7 = s6; i7 = i6; s6 = s5; i6 = i5; s5 = s4; i5 = i4;
            s4 = s3; i4 = i3; s3 = s2; i3 = i2; s2 = s1; i2 = i1;
            s1 = s0; i1 = i0; s0 = -INFINITY; i0 = 0x7fffffff;
            hv = s7; hi = i7;
        }
    }

    if (r == 0) {
        const int token = tok0 + t;
        float raw[8];
        float mx = -INFINITY;
        #pragma unroll
        for (int k = 0; k < 8; ++k) {
            raw[k] = (topv[k] - lr[topi[k]]) * SCALE;  // unbias: attn score excludes reliability
            mx = fmaxf(mx, raw[k]);
        }
        float e[8]; float sum = 0.f;
        #pragma unroll
        for (int k = 0; k < 8; ++k) { e[k] = expf(raw[k] - mx); sum += e[k]; }
        float inv = 1.0f / sum;
        #pragma unroll
        for (int k = 0; k < 8; ++k) {
            float w = e[k] * inv;
            wout[(size_t)token * 8 + k]  = w;
            wws[(size_t)token * 8 + k]   = w;
            idxws[(size_t)token * 8 + k] = topi[k];
        }
    }
}

// ---------------- kernel 2: weighted value gather ----------------
// One block per token; 256 threads x float4 = 1024 outputs. V rows are
// L2/L3-resident (16.8 MB total), reads per row fully coalesced.
__launch_bounds__(256)
__global__ void gather_kernel(const float* __restrict__ values,
                              const int*   __restrict__ idxws,
                              const float* __restrict__ wws,
                              float* __restrict__ out) {
    const int token = blockIdx.x;
    __shared__ int   sidx[8];
    __shared__ float sw[8];
    if (threadIdx.x < 8) {
        sidx[threadIdx.x] = idxws[(size_t)token * 8 + threadIdx.x];
        sw[threadIdx.x]   = wws[(size_t)token * 8 + threadIdx.x];
    }
    __syncthreads();
    const int h4 = threadIdx.x;
    const float4* V4 = (const float4*)values;
    float4 acc = make_float4(0.f, 0.f, 0.f, 0.f);
    #pragma unroll
    for (int k = 0; k < 8; ++k) {
        float4 v = V4[(size_t)sidx[k] * 256 + h4];
        float  w = sw[k];
        acc.x = fmaf(w, v.x, acc.x);
        acc.y = fmaf(w, v.y, acc.y);
        acc.z = fmaf(w, v.z, acc.z);
        acc.w = fmaf(w, v.w, acc.w);
    }
    ((float4*)out)[(size_t)token * 256 + h4] = acc;
}

// ---------------- launch ----------------
extern "C" void kernel_launch(void* const* d_in, const int* in_sizes, int n_in,
                              void* d_out, int out_size, void* d_ws, size_t ws_size,
                              hipStream_t stream) {
    const float* query  = (const float*)d_in[0];
    const float* keys   = (const float*)d_in[1];
    const float* values = (const float*)d_in[2];
    const float* rel    = (const float*)d_in[3];

    float* out  = (float*)d_out;                 // [16384, 1024]
    float* wout = out + (size_t)NTOK * HDIM;     // [16384, 8]

    float* lr    = (float*)d_ws;                                   // 4096 f32
    int*   idxws = (int*)((char*)d_ws + NSLOTS * 4);               // 16384*8 i32
    float* wws   = (float*)((char*)d_ws + NSLOTS * 4 + NTOK * 8 * 4);

    hipLaunchKernelGGL(lr_kernel, dim3(16), dim3(256), 0, stream, rel, lr);
    hipLaunchKernelGGL(route_kernel, dim3(NTOK / 16), dim3(256), 0, stream,
                       query, keys, lr, wout, idxws, wws);
    hipLaunchKernelGGL(gather_kernel, dim3(NTOK), dim3(256), 0, stream,
                       values, idxws, wws, out);
}

// Round 2
// 798.452 us; speedup vs baseline: 4.6545x; 4.6545x over previous
//
#include <hip/hip_runtime.h>
#include <math.h>

#define NSLOTS 4096
#define DIM    128
#define HDIM   1024
#define NTOK   16384   // 4 * 4096
#define SCALE  0.08838834764831845f  // 1/sqrt(128)
#define REPS   1e-10f

#define TPB    32               // tokens per block
#define TROWS  64               // K-tile rows staged in LDS
#define NTILES (NSLOTS / TROWS) // 64
#define QPAD   132              // 128 floats + 1 float4 pad (row stride)

// ---------------- kernel 0: log-reliability precompute ----------------
__global__ void lr_kernel(const float* __restrict__ rel, float* __restrict__ lr) {
    int j = blockIdx.x * 256 + threadIdx.x;
    if (j < NSLOTS) lr[j] = logf(rel[j] + REPS);
}

// Sorted-ascending top-8 insert (s[0] = smallest). Strict '>' keeps the
// earlier (lower) index above on ties -> matches stable jax.lax.top_k.
__device__ __forceinline__ void insert8(float (&s)[8], int (&ix)[8], float sc, int j) {
    if (sc > s[0]) {
        s[0] = sc; ix[0] = j;
        #pragma unroll
        for (int m = 0; m < 7; ++m) {
            if (s[m] > s[m + 1]) {
                float tf = s[m]; s[m] = s[m + 1]; s[m + 1] = tf;
                int   ti = ix[m]; ix[m] = ix[m + 1]; ix[m + 1] = ti;
            }
        }
    }
}

// Stable pop-merge of 16 lanes' sorted top-8 (within a 16-lane group),
// then softmax on unbiased scores + store (lane r==0 of the group).
__device__ __forceinline__ void merge_softmax_store(
        float (&s)[8], int (&ix)[8], int r, int token,
        const float* __restrict__ lr, float* __restrict__ wout,
        int* __restrict__ idxws, float* __restrict__ wws) {
    float hv = s[7]; int hi = ix[7];
    float topv[8]; int topi[8];
    #pragma unroll
    for (int round = 0; round < 8; ++round) {
        float bv = hv; int bi = hi;
        #pragma unroll
        for (int off = 1; off < 16; off <<= 1) {
            float ov = __shfl_xor(bv, off, 16);
            int   oi = __shfl_xor(bi, off, 16);
            if (ov > bv || (ov == bv && oi < bi)) { bv = ov; bi = oi; }
        }
        topv[round] = bv; topi[round] = bi;
        if (hv == bv && hi == bi) {   // I won: pop my head
            #pragma unroll
            for (int m = 7; m > 0; --m) { s[m] = s[m - 1]; ix[m] = ix[m - 1]; }
            s[0] = -INFINITY; ix[0] = 0x7fffffff;
            hv = s[7]; hi = ix[7];
        }
    }
    if (r == 0) {
        float raw[8]; float mx = -INFINITY;
        #pragma unroll
        for (int k = 0; k < 8; ++k) {
            raw[k] = (topv[k] - lr[topi[k]]) * SCALE;  // attn score excludes reliability bias
            mx = fmaxf(mx, raw[k]);
        }
        float e[8]; float sum = 0.f;
        #pragma unroll
        for (int k = 0; k < 8; ++k) { e[k] = expf(raw[k] - mx); sum += e[k]; }
        float inv = 1.0f / sum;
        #pragma unroll
        for (int k = 0; k < 8; ++k) {
            float w = e[k] * inv;
            wout[(size_t)token * 8 + k]  = w;
            wws[(size_t)token * 8 + k]   = w;
            idxws[(size_t)token * 8 + k] = topi[k];
        }
    }
}

// ---------------- kernel 1: fused router GEMM + top-8 + softmax ----------------
// 256 threads = 16 groups (tg) x 16 residues (r). Thread handles tokens
// {tg, tg+16} x tile rows {r, r+16, r+32, r+48}. K-tiles (64x128 f32) are
// register-prefetched from global (coalesced float4, L2-resident) and staged
// in LDS with +1-float4 row padding. Within a wave, 4 tg-lanes share each k
// row -> LDS broadcast; residue stride 16*132 floats -> free 2-way aliasing.
__launch_bounds__(256)
__global__ void route_kernel(const float* __restrict__ query,
                             const float* __restrict__ keys,
                             const float* __restrict__ lr,
                             float* __restrict__ wout,
                             int*   __restrict__ idxws,
                             float* __restrict__ wws) {
    __shared__ float qs[TPB * QPAD];    // 32 tokens x 128 (padded)
    __shared__ float kt[TROWS * QPAD];  // 64 rows   x 128 (padded)
    const int tid  = threadIdx.x;
    const int tok0 = blockIdx.x * TPB;

    // stage Q: 32 tokens x 32 float4 = 1024 float4, coalesced
    const float4* qsrc = (const float4*)(query + (size_t)tok0 * DIM);
    #pragma unroll
    for (int i = 0; i < 4; ++i) {
        int idx = tid + i * 256;
        int t = idx >> 5, d4 = idx & 31;
        ((float4*)(qs + t * QPAD))[d4] = qsrc[idx];
    }

    const int r  = tid & 15;
    const int tg = tid >> 4;

    // prefetch K-tile 0 into registers
    const float4* K4 = (const float4*)keys;
    float4 stg[8];
    #pragma unroll
    for (int i = 0; i < 8; ++i) stg[i] = K4[tid + i * 256];

    float sA[8], sB[8]; int iA[8], iB[8];
    #pragma unroll
    for (int m = 0; m < 8; ++m) {
        sA[m] = -INFINITY; sB[m] = -INFINITY;
        iA[m] = 0x7fffffff; iB[m] = 0x7fffffff;
    }

    const float4* qa = (const float4*)(qs + tg * QPAD);
    const float4* qb = (const float4*)(qs + (tg + 16) * QPAD);

    for (int tile = 0; tile < NTILES; ++tile) {
        __syncthreads();   // prior compute done (iter 0: also fences qs writes)
        #pragma unroll
        for (int i = 0; i < 8; ++i) {
            int idx = tid + i * 256;
            int row = idx >> 5, c4 = idx & 31;
            ((float4*)(kt + row * QPAD))[c4] = stg[i];
        }
        __syncthreads();
        if (tile < NTILES - 1) {   // issue next tile's global loads; compute hides latency
            const float4* src = K4 + (size_t)(tile + 1) * (TROWS * 32);
            #pragma unroll
            for (int i = 0; i < 8; ++i) stg[i] = src[tid + i * 256];
        }

        const int j0 = tile * TROWS + r;
        float lrv0 = lr[j0], lrv1 = lr[j0 + 16], lrv2 = lr[j0 + 32], lrv3 = lr[j0 + 48];

        const float4* k0 = (const float4*)(kt + r * QPAD);
        const float4* k1 = (const float4*)(kt + (r + 16) * QPAD);
        const float4* k2 = (const float4*)(kt + (r + 32) * QPAD);
        const float4* k3 = (const float4*)(kt + (r + 48) * QPAD);

        float accA0 = 0.f, accA1 = 0.f, accA2 = 0.f, accA3 = 0.f;
        float accB0 = 0.f, accB1 = 0.f, accB2 = 0.f, accB3 = 0.f;
        #pragma unroll 4
        for (int d4 = 0; d4 < 32; ++d4) {
            float4 qva = qa[d4];
            float4 qvb = qb[d4];
            float4 kv;
            kv = k0[d4];
            accA0 = fmaf(qva.x, kv.x, accA0); accA0 = fmaf(qva.y, kv.y, accA0);
            accA0 = fmaf(qva.z, kv.z, accA0); accA0 = fmaf(qva.w, kv.w, accA0);
            accB0 = fmaf(qvb.x, kv.x, accB0); accB0 = fmaf(qvb.y, kv.y, accB0);
            accB0 = fmaf(qvb.z, kv.z, accB0); accB0 = fmaf(qvb.w, kv.w, accB0);
            kv = k1[d4];
            accA1 = fmaf(qva.x, kv.x, accA1); accA1 = fmaf(qva.y, kv.y, accA1);
            accA1 = fmaf(qva.z, kv.z, accA1); accA1 = fmaf(qva.w, kv.w, accA1);
            accB1 = fmaf(qvb.x, kv.x, accB1); accB1 = fmaf(qvb.y, kv.y, accB1);
            accB1 = fmaf(qvb.z, kv.z, accB1); accB1 = fmaf(qvb.w, kv.w, accB1);
            kv = k2[d4];
            accA2 = fmaf(qva.x, kv.x, accA2); accA2 = fmaf(qva.y, kv.y, accA2);
            accA2 = fmaf(qva.z, kv.z, accA2); accA2 = fmaf(qva.w, kv.w, accA2);
            accB2 = fmaf(qvb.x, kv.x, accB2); accB2 = fmaf(qvb.y, kv.y, accB2);
            accB2 = fmaf(qvb.z, kv.z, accB2); accB2 = fmaf(qvb.w, kv.w, accB2);
            kv = k3[d4];
            accA3 = fmaf(qva.x, kv.x, accA3); accA3 = fmaf(qva.y, kv.y, accA3);
            accA3 = fmaf(qva.z, kv.z, accA3); accA3 = fmaf(qva.w, kv.w, accA3);
            accB3 = fmaf(qvb.x, kv.x, accB3); accB3 = fmaf(qvb.y, kv.y, accB3);
            accB3 = fmaf(qvb.z, kv.z, accB3); accB3 = fmaf(qvb.w, kv.w, accB3);
        }
        insert8(sA, iA, accA0 + lrv0, j0);
        insert8(sA, iA, accA1 + lrv1, j0 + 16);
        insert8(sA, iA, accA2 + lrv2, j0 + 32);
        insert8(sA, iA, accA3 + lrv3, j0 + 48);
        insert8(sB, iB, accB0 + lrv0, j0);
        insert8(sB, iB, accB1 + lrv1, j0 + 16);
        insert8(sB, iB, accB2 + lrv2, j0 + 32);
        insert8(sB, iB, accB3 + lrv3, j0 + 48);
    }

    merge_softmax_store(sA, iA, r, tok0 + tg,      lr, wout, idxws, wws);
    merge_softmax_store(sB, iB, r, tok0 + tg + 16, lr, wout, idxws, wws);
}

// ---------------- kernel 2: weighted value gather ----------------
__launch_bounds__(256)
__global__ void gather_kernel(const float* __restrict__ values,
                              const int*   __restrict__ idxws,
                              const float* __restrict__ wws,
                              float* __restrict__ out) {
    const int token = blockIdx.x;
    __shared__ int   sidx[8];
    __shared__ float sw[8];
    if (threadIdx.x < 8) {
        sidx[threadIdx.x] = idxws[(size_t)token * 8 + threadIdx.x];
        sw[threadIdx.x]   = wws[(size_t)token * 8 + threadIdx.x];
    }
    __syncthreads();
    const int h4 = threadIdx.x;
    const float4* V4 = (const float4*)values;
    float4 acc = make_float4(0.f, 0.f, 0.f, 0.f);
    #pragma unroll
    for (int k = 0; k < 8; ++k) {
        float4 v = V4[(size_t)sidx[k] * 256 + h4];
        float  w = sw[k];
        acc.x = fmaf(w, v.x, acc.x);
        acc.y = fmaf(w, v.y, acc.y);
        acc.z = fmaf(w, v.z, acc.z);
        acc.w = fmaf(w, v.w, acc.w);
    }
    ((float4*)out)[(size_t)token * 256 + h4] = acc;
}

// ---------------- launch ----------------
extern "C" void kernel_launch(void* const* d_in, const int* in_sizes, int n_in,
                              void* d_out, int out_size, void* d_ws, size_t ws_size,
                              hipStream_t stream) {
    const float* query  = (const float*)d_in[0];
    const float* keys   = (const float*)d_in[1];
    const float* values = (const float*)d_in[2];
    const float* rel    = (const float*)d_in[3];

    float* out  = (float*)d_out;                 // [16384, 1024]
    float* wout = out + (size_t)NTOK * HDIM;     // [16384, 8]

    float* lr    = (float*)d_ws;                                   // 4096 f32
    int*   idxws = (int*)((char*)d_ws + NSLOTS * 4);               // 16384*8 i32
    float* wws   = (float*)((char*)d_ws + NSLOTS * 4 + NTOK * 8 * 4);

    hipLaunchKernelGGL(lr_kernel, dim3(16), dim3(256), 0, stream, rel, lr);
    hipLaunchKernelGGL(route_kernel, dim3(NTOK / TPB), dim3(256), 0, stream,
                       query, keys, lr, wout, idxws, wws);
    hipLaunchKernelGGL(gather_kernel, dim3(NTOK), dim3(256), 0, stream,
                       values, idxws, wws, out);
}

// Round 3
// 441.033 us; speedup vs baseline: 8.4266x; 1.8104x over previous
//
#include <hip/hip_runtime.h>
#include <math.h>

#define NSLOTS 4096
#define DIM    128
#define HDIM   1024
#define NTOK   16384   // 4 * 4096
#define SCALE  0.08838834764831845f  // 1/sqrt(128)
#define REPS   1e-10f

typedef __attribute__((ext_vector_type(8))) short bf16x8;
typedef __attribute__((ext_vector_type(4))) float f32x4;

#define LROW 136   // ushorts per LDS k-row: 128 bf16 + 8 pad (272 B) -> conflict-free b128

// ---------------- top-8 state: named scalars (spill-proof) ----------------
struct Top8 {
    float s0,s1,s2,s3,s4,s5,s6,s7;   // ascending, s7 = max
    int   i0,i1,i2,i3,i4,i5,i6,i7;
};
__device__ __forceinline__ void top8_init(Top8& T) {
    T.s0=T.s1=T.s2=T.s3=T.s4=T.s5=T.s6=T.s7 = -INFINITY;
    T.i0=T.i1=T.i2=T.i3=T.i4=T.i5=T.i6=T.i7 = 0x7fffffff;
}
#define CSW(a,b,x,y) { if (a > b) { float tf=a; a=b; b=tf; int ti=x; x=y; y=ti; } }
// strict '>' keeps earlier (lower) index on ties -> stable like jax.lax.top_k
__device__ __forceinline__ void ins8(Top8& T, float sc, int j) {
    if (sc > T.s0) {
        T.s0 = sc; T.i0 = j;
        CSW(T.s0,T.s1,T.i0,T.i1); CSW(T.s1,T.s2,T.i1,T.i2); CSW(T.s2,T.s3,T.i2,T.i3);
        CSW(T.s3,T.s4,T.i3,T.i4); CSW(T.s4,T.s5,T.i4,T.i5); CSW(T.s5,T.s6,T.i5,T.i6);
        CSW(T.s6,T.s7,T.i6,T.i7);
    }
}
// Pop-merge 16 lanes' sorted top-8 -> top-16 (desc); round-c winner written by
// lane m==c straight to LDS (no runtime-indexed register arrays -> no scratch).
__device__ __forceinline__ void popmerge16(Top8& T, int m, float* outS, int* outI) {
    float hv = T.s7; int hi = T.i7;
    #pragma unroll
    for (int rnd = 0; rnd < 16; ++rnd) {
        float bv = hv; int bi = hi;
        #pragma unroll
        for (int off = 1; off < 16; off <<= 1) {
            float ov = __shfl_xor(bv, off, 16);
            int   oi = __shfl_xor(bi, off, 16);
            if (ov > bv || (ov == bv && oi < bi)) { bv = ov; bi = oi; }
        }
        if (m == rnd) { outS[rnd] = bv; outI[rnd] = bi; }
        if (hv == bv && hi == bi) {   // I won: pop my head
            T.s7=T.s6; T.i7=T.i6; T.s6=T.s5; T.i6=T.i5; T.s5=T.s4; T.i5=T.i4;
            T.s4=T.s3; T.i4=T.i3; T.s3=T.s2; T.i3=T.i2; T.s2=T.s1; T.i2=T.i1;
            T.s1=T.s0; T.i1=T.i0; T.s0=-INFINITY; T.i0=0x7fffffff;
            hv = T.s7; hi = T.i7;
        }
    }
}

// ---------------- kernel 0: prep (bf16 convert + log-reliability) ----------
__device__ __forceinline__ ushort f2bf(float f) {   // RNE, matches HW cvt
    unsigned u = __float_as_uint(f);
    return (ushort)((u + 0x7fffu + ((u >> 16) & 1u)) >> 16);
}
__global__ void prep_kernel(const float* __restrict__ q, const float* __restrict__ k,
                            const float* __restrict__ rel,
                            ushort* __restrict__ qb, ushort* __restrict__ kb,
                            float* __restrict__ lr) {
    int gid = blockIdx.x * 256 + threadIdx.x;
    if (gid < 524288) {                       // q: 2,097,152 floats as float4
        float4 v = ((const float4*)q)[gid];
        ushort4 o; o.x=f2bf(v.x); o.y=f2bf(v.y); o.z=f2bf(v.z); o.w=f2bf(v.w);
        ((ushort4*)qb)[gid] = o;
    } else if (gid < 524288 + 131072) {       // keys: 524,288 floats as float4
        int g = gid - 524288;
        float4 v = ((const float4*)k)[g];
        ushort4 o; o.x=f2bf(v.x); o.y=f2bf(v.y); o.z=f2bf(v.z); o.w=f2bf(v.w);
        ((ushort4*)kb)[g] = o;
    } else if (gid < 524288 + 131072 + 4096) {
        int g = gid - 524288 - 131072;
        lr[g] = logf(rel[g] + REPS);
    }
}

// ---------------- kernel 1: MFMA router + per-column top-8 + merge ----------
// Block: 256 thr = 4 waves = 2 token-sets (16 tokens) x 2 slot-halves (2048).
// Per wave: A-frags (16 tokens x K=128 bf16) stationary in VGPRs; B (keys)
// staged per 64-slot tile in LDS (padded rows), 1 ds_read_b128 per MFMA.
// C/D layout (m89/m91): col=lane&15, row=(lane>>4)*4+reg.
__launch_bounds__(256, 2)
__global__ void route_kernel(const ushort* __restrict__ qb,
                             const ushort* __restrict__ kb,
                             const float*  __restrict__ lr,
                             int* __restrict__ cand) {
    __shared__ ushort ktile[2][64 * LROW];     // 2 x 17,408 B
    __shared__ float  mS[32][2][16];           // per-token per-half sorted top-16
    __shared__ int    mI[32][2][16];

    const int tid  = threadIdx.x;
    const int lane = tid & 63;
    const int w    = tid >> 6;
    const int ts   = w >> 1;          // token-set 0/1
    const int half = w & 1;           // slot half 0/1
    const int tokbase = blockIdx.x * 32 + ts * 16;
    const int m    = lane & 15;       // col / row-in-tile index
    const int kseg = lane >> 4;       // k-segment 0..3

    // A-frags: q_bf16[tokbase+m][kc*32 + kseg*8 .. +8), contiguous 16 B
    bf16x8 aF[4];
    const ushort* qrow = qb + (size_t)(tokbase + m) * DIM + kseg * 8;
    #pragma unroll
    for (int kc = 0; kc < 4; ++kc)
        aF[kc] = *(const bf16x8*)(qrow + kc * 32);

    Top8 st0, st1, st2, st3;
    top8_init(st0); top8_init(st1); top8_init(st2); top8_init(st3);

    // staging: the 2 waves of each half cooperatively stage their 64x128 bf16 tile
    const int laneInPair = ts * 64 + lane;                 // 0..127 within half
    const ushort* ksrc = kb + (size_t)half * (2048 * DIM);
    ushort* klds = &ktile[half][0];

    const float4* gsrc0 = (const float4*)ksrc;             // 16 KB tile = 1024 f4
    float4 stg[8];
    #pragma unroll
    for (int i = 0; i < 8; ++i) stg[i] = gsrc0[laneInPair + i * 128];

    for (int tile = 0; tile < 32; ++tile) {
        __syncthreads();
        #pragma unroll
        for (int i = 0; i < 8; ++i) {
            int g = laneInPair + i * 128;                  // 16-B segment id
            *(float4*)(klds + (g >> 4) * LROW + (g & 15) * 8) = stg[i];
        }
        __syncthreads();
        if (tile < 31) {
            const float4* gsrc = (const float4*)(ksrc + (size_t)(tile + 1) * (64 * DIM));
            #pragma unroll
            for (int i = 0; i < 8; ++i) stg[i] = gsrc[laneInPair + i * 128];
        }

        #pragma unroll
        for (int sub = 0; sub < 4; ++sub) {
            f32x4 acc = {0.f, 0.f, 0.f, 0.f};
            const ushort* brow = klds + (sub * 16 + m) * LROW + kseg * 8;
            #pragma unroll
            for (int kc = 0; kc < 4; ++kc) {
                bf16x8 bF = *(const bf16x8*)(brow + kc * 32);
                acc = __builtin_amdgcn_mfma_f32_16x16x32_bf16(aF[kc], bF, acc, 0, 0, 0);
            }
            int slot = half * 2048 + tile * 64 + sub * 16 + m;
            float lrv = lr[slot];
            ins8(st0, acc[0] + lrv, slot);   // reg r -> token row kseg*4+r
            ins8(st1, acc[1] + lrv, slot);
            ins8(st2, acc[2] + lrv, slot);
            ins8(st3, acc[3] + lrv, slot);
        }
    }

    // per-wave: merge 16 column-lanes' top-8 -> sorted top-16 per token (this half)
    popmerge16(st0, m, &mS[ts*16 + kseg*4 + 0][half][0], &mI[ts*16 + kseg*4 + 0][half][0]);
    popmerge16(st1, m, &mS[ts*16 + kseg*4 + 1][half][0], &mI[ts*16 + kseg*4 + 1][half][0]);
    popmerge16(st2, m, &mS[ts*16 + kseg*4 + 2][half][0], &mI[ts*16 + kseg*4 + 2][half][0]);
    popmerge16(st3, m, &mS[ts*16 + kseg*4 + 3][half][0], &mI[ts*16 + kseg*4 + 3][half][0]);

    __syncthreads();

    // cross-half 2-way merge of sorted-16 lists -> approx-top-16 candidate idx
    if (tid < 32) {
        int token = blockIdx.x * 32 + tid;
        int pa = 0, pb = 0;
        #pragma unroll
        for (int c = 0; c < 16; ++c) {
            bool ta;
            if (pa >= 16) ta = false;
            else if (pb >= 16) ta = true;
            else ta = (mS[tid][0][pa] >= mS[tid][1][pb]);  // tie -> half0 (lower idx)
            int ci = ta ? mI[tid][0][pa] : mI[tid][1][pb];
            cand[(size_t)token * 16 + c] = ci;
            if (ta) ++pa; else ++pb;
        }
    }
}

// ---------------- kernel 2: exact fp32 rescue + final top-8 + softmax -------
// 1 wave per token; lane = cand(16) x quarter(4). Recompute q.k exactly in
// fp32, re-rank 16 candidates by biased score (desc, idx asc), softmax on raw.
__launch_bounds__(256)
__global__ void rescue_kernel(const float* __restrict__ query,
                              const float* __restrict__ keys,
                              const float* __restrict__ lr,
                              const int*   __restrict__ cand,
                              float* __restrict__ wout,
                              int*   __restrict__ idxws) {
    __shared__ float bs[4][16], rs[4][16];
    __shared__ int   cs[4][16];
    const int tid  = threadIdx.x;
    const int w    = tid >> 6;
    const int lane = tid & 63;
    const int token = blockIdx.x * 4 + w;
    const int c  = lane >> 2;
    const int qp = lane & 3;

    int ci = cand[(size_t)token * 16 + c];
    const float4* q4 = (const float4*)(query + (size_t)token * DIM) + qp * 8;
    const float4* k4 = (const float4*)(keys  + (size_t)ci    * DIM) + qp * 8;
    float sum = 0.f;
    #pragma unroll
    for (int i = 0; i < 8; ++i) {
        float4 a = q4[i], b = k4[i];
        sum = fmaf(a.x, b.x, sum); sum = fmaf(a.y, b.y, sum);
        sum = fmaf(a.z, b.z, sum); sum = fmaf(a.w, b.w, sum);
    }
    sum += __shfl_xor(sum, 1, 4);
    sum += __shfl_xor(sum, 2, 4);
    if (qp == 0) { rs[w][c] = sum; bs[w][c] = sum + lr[ci]; cs[w][c] = ci; }
    __syncthreads();

    if (lane == 0) {
        unsigned used = 0;
        float rsel[8]; int isel[8];
        float mx = -INFINITY;
        #pragma unroll
        for (int k = 0; k < 8; ++k) {
            float bb = -INFINITY; int bj = 0x7fffffff; int bc = 0;
            for (int c2 = 0; c2 < 16; ++c2) {
                if (used & (1u << c2)) continue;
                float b = bs[w][c2]; int j = cs[w][c2];
                if (b > bb || (b == bb && j < bj)) { bb = b; bj = j; bc = c2; }
            }
            used |= 1u << bc;
            rsel[k] = rs[w][bc] * SCALE;
            isel[k] = bj;
            mx = fmaxf(mx, rsel[k]);
        }
        float e[8]; float s = 0.f;
        #pragma unroll
        for (int k = 0; k < 8; ++k) { e[k] = expf(rsel[k] - mx); s += e[k]; }
        float inv = 1.0f / s;
        #pragma unroll
        for (int k = 0; k < 8; ++k) {
            wout[(size_t)token * 8 + k]  = e[k] * inv;
            idxws[(size_t)token * 8 + k] = isel[k];
        }
    }
}

// ---------------- kernel 3: weighted value gather ----------------
__launch_bounds__(256)
__global__ void gather_kernel(const float* __restrict__ values,
                              const int*   __restrict__ idxws,
                              const float* __restrict__ wout,
                              float* __restrict__ out) {
    const int token = blockIdx.x;
    __shared__ int   sidx[8];
    __shared__ float sw[8];
    if (threadIdx.x < 8) {
        sidx[threadIdx.x] = idxws[(size_t)token * 8 + threadIdx.x];
        sw[threadIdx.x]   = wout[(size_t)token * 8 + threadIdx.x];
    }
    __syncthreads();
    const int h4 = threadIdx.x;
    const float4* V4 = (const float4*)values;
    float4 acc = make_float4(0.f, 0.f, 0.f, 0.f);
    #pragma unroll
    for (int k = 0; k < 8; ++k) {
        float4 v = V4[(size_t)sidx[k] * 256 + h4];
        float  ww = sw[k];
        acc.x = fmaf(ww, v.x, acc.x);
        acc.y = fmaf(ww, v.y, acc.y);
        acc.z = fmaf(ww, v.z, acc.z);
        acc.w = fmaf(ww, v.w, acc.w);
    }
    ((float4*)out)[(size_t)token * 256 + h4] = acc;
}

// ---------------- launch ----------------
extern "C" void kernel_launch(void* const* d_in, const int* in_sizes, int n_in,
                              void* d_out, int out_size, void* d_ws, size_t ws_size,
                              hipStream_t stream) {
    const float* query  = (const float*)d_in[0];
    const float* keys   = (const float*)d_in[1];
    const float* values = (const float*)d_in[2];
    const float* rel    = (const float*)d_in[3];

    float* out  = (float*)d_out;                 // [16384, 1024]
    float* wout = out + (size_t)NTOK * HDIM;     // [16384, 8]

    char* ws = (char*)d_ws;
    float*  lr    = (float*)ws;                     ws += 4096 * 4;          // 16 KB
    ushort* qb    = (ushort*)ws;                    ws += (size_t)NTOK * DIM * 2;   // 4 MB
    ushort* kb    = (ushort*)ws;                    ws += (size_t)NSLOTS * DIM * 2; // 1 MB
    int*    cand  = (int*)ws;                       ws += (size_t)NTOK * 16 * 4;    // 1 MB
    int*    idxws = (int*)ws;

    int prep_grid = (524288 + 131072 + 4096 + 255) / 256;
    hipLaunchKernelGGL(prep_kernel, dim3(prep_grid), dim3(256), 0, stream,
                       query, keys, rel, qb, kb, lr);
    hipLaunchKernelGGL(route_kernel, dim3(NTOK / 32), dim3(256), 0, stream,
                       qb, kb, lr, cand);
    hipLaunchKernelGGL(rescue_kernel, dim3(NTOK / 4), dim3(256), 0, stream,
                       query, keys, lr, cand, wout, idxws);
    hipLaunchKernelGGL(gather_kernel, dim3(NTOK), dim3(256), 0, stream,
                       values, idxws, wout, out);
}

// Round 5
// 275.533 us; speedup vs baseline: 13.4881x; 1.6007x over previous
//
#include <hip/hip_runtime.h>
#include <math.h>

#define NSLOTS 4096
#define DIM    128
#define HDIM   1024
#define NTOK   16384   // 4 * 4096
#define SCALE  0.08838834764831845f  // 1/sqrt(128)
#define REPS   1e-10f

typedef __attribute__((ext_vector_type(8))) short bf16x8;
typedef __attribute__((ext_vector_type(4))) float f32x4;

typedef __attribute__((address_space(1))) const void* as1cv;
typedef __attribute__((address_space(3))) void* as3v;

// ---- packed (score | 4095-slot) helpers -----------------------------------
// Low 12 mantissa bits replaced by (4095-slot): float compare = score desc,
// then slot asc (exact for positives; negative-score tie order flips, but the
// fp32 rescue re-ranks the 32-candidate pool exactly, so only pool membership
// at the noise margin matters — covered by the top-16-per-half pool width).
__device__ __forceinline__ float pack_score(float biased, unsigned inv_idx) {
    return __uint_as_float((__float_as_uint(biased) & 0xFFFFF000u) | inv_idx);
}
#define PACK_NEG_INF __uint_as_float(0xFF7FF000u)   // ~ -FLT_MAX, valid finite

// Branchless insert into ascending sorted r[0..7] (r[7]=max), drop min.
__device__ __forceinline__ void ins_packed(float (&r)[8], float x) {
    #pragma unroll
    for (int i = 0; i < 7; ++i) r[i] = fminf(fmaxf(r[i], x), r[i + 1]);
    r[7] = fmaxf(r[7], x);
}

// Pop-merge 4 kseg-lanes' sorted top-8 (32 values) -> this half's top-16 slot
// indices, written straight to cand. Group = lanes {l, l^16, l^32, l^48}.
__device__ __forceinline__ void merge_out16(float (&r)[8], int kseg, int token,
                                            int half, int* __restrict__ cand) {
    float hv = r[7];
    #pragma unroll
    for (int rnd = 0; rnd < 16; ++rnd) {
        float bv = hv;
        bv = fmaxf(bv, __shfl_xor(bv, 16, 64));
        bv = fmaxf(bv, __shfl_xor(bv, 32, 64));
        if ((rnd >> 2) == kseg) {   // each kseg-lane writes 4 of the 16
            int slot = 4095 - (int)(__float_as_uint(bv) & 0xFFFu);
            cand[(size_t)token * 32 + half * 16 + rnd] = slot;
        }
        if (hv == bv) {   // my head won (packed values distinct in group): pop
            #pragma unroll
            for (int m2 = 7; m2 > 0; --m2) r[m2] = r[m2 - 1];
            r[0] = PACK_NEG_INF;
            hv = r[7];
        }
    }
}

// ---------------- kernel 0: prep (bf16 convert + K permute + log-rel) -------
__device__ __forceinline__ ushort f2bf(float f) {   // RNE
    unsigned u = __float_as_uint(f);
    return (ushort)((u + 0x7fffu + ((u >> 16) & 1u)) >> 16);
}
// kbp chunk C (16 B = 8 bf16): C = h*32768 + t*1024 + f*64 + l
//   l=lane (m=l&15, kseg=l>>4), f=(sub<<2)|kc, t=tile, h=half
//   source = keys[slot=h*2048+t*64+sub*16+m][kc*32+kseg*8 .. +8)
__global__ void prep_kernel(const float* __restrict__ q, const float* __restrict__ k,
                            const float* __restrict__ rel,
                            ushort* __restrict__ qb, ushort* __restrict__ kbp,
                            float* __restrict__ lr) {
    int gid = blockIdx.x * 256 + threadIdx.x;
    if (gid < 524288) {                       // qb row-major: 2,097,152 floats / 4
        float4 v = ((const float4*)q)[gid];
        ushort4 o; o.x = f2bf(v.x); o.y = f2bf(v.y); o.z = f2bf(v.z); o.w = f2bf(v.w);
        ((ushort4*)qb)[gid] = o;
    } else if (gid < 524288 + 65536) {        // kbp fragment-permuted chunks
        int C = gid - 524288;
        int l = C & 63, f = (C >> 6) & 15, t = (C >> 10) & 31, h = (C >> 15) & 1;
        int m = l & 15, kseg = l >> 4, sub = f >> 2, kc = f & 3;
        int slot = h * 2048 + t * 64 + sub * 16 + m;
        const float4* src = (const float4*)(k + (size_t)slot * DIM + kc * 32 + kseg * 8);
        float4 v0 = src[0], v1 = src[1];
        union { ushort u[8]; uint4 v; } o;
        o.u[0] = f2bf(v0.x); o.u[1] = f2bf(v0.y); o.u[2] = f2bf(v0.z); o.u[3] = f2bf(v0.w);
        o.u[4] = f2bf(v1.x); o.u[5] = f2bf(v1.y); o.u[6] = f2bf(v1.z); o.u[7] = f2bf(v1.w);
        ((uint4*)kbp)[C] = o.v;
    } else if (gid < 524288 + 65536 + 4096) {
        int g = gid - 524288 - 65536;
        lr[g] = logf(rel[g] + REPS);
    }
}

// ---------------- kernel 1: MFMA router + packed top-8 ----------------------
// 256 thr = 4 waves: half = w&1 (slot half of 2048), tset = w>>1 (32 tokens).
// A = keys (DMA-staged LDS tiles, 64 slots), B = queries (stationary VGPRs,
// 2 sets x 16 tokens). D: row=slot=(lane>>4)*4+reg, col=token=lane&15 ->
// each lane owns 1 token/set, slot partition (slot%16) in [kseg*4,kseg*4+4)
// (512 slots). Per-lane top-8 covers any true-top-8 member of the partition;
// the 4-lane merge keeps 16 per half -> 32-candidate pool, rescued in fp32.
__launch_bounds__(256, 2)
__global__ void route_kernel(const ushort* __restrict__ qb,
                             const ushort* __restrict__ kbp,
                             const float*  __restrict__ lr,
                             int* __restrict__ cand) {
    __shared__ ushort ktile[2][2][16 * 512];   // [half][buf][frag*512] = 64 KB
    const int tid  = threadIdx.x;
    const int lane = tid & 63;
    const int w    = tid >> 6;
    const int half = w & 1;
    const int tset = w >> 1;
    const int m    = lane & 15;
    const int kseg = lane >> 4;
    const int tokbase = blockIdx.x * 64 + tset * 32;

    // stationary B-frags (queries): lane (n=m, kseg) needs Q[tok][kc*32+kseg*8..+8)
    bf16x8 bF[2][4];
    #pragma unroll
    for (int s = 0; s < 2; ++s) {
        const ushort* qrow = qb + (size_t)(tokbase + s * 16 + m) * DIM + kseg * 8;
        #pragma unroll
        for (int kc = 0; kc < 4; ++kc)
            bF[s][kc] = *(const bf16x8*)(qrow + kc * 32);
    }

    float R0[8], R1[8];
    #pragma unroll
    for (int i = 0; i < 8; ++i) { R0[i] = PACK_NEG_INF; R1[i] = PACK_NEG_INF; }

    // DMA: wave (half,tset) stages frags [tset*8, tset*8+8) of its half's tile
    auto issue = [&](int t, int buf) {
        const ushort* gt = kbp + (((size_t)(half * 32 + t) * 16 + tset * 8) << 9) + lane * 8;
        ushort* lbase = &ktile[half][buf][tset * 8 * 512];
        #pragma unroll
        for (int i = 0; i < 8; ++i) {
            __builtin_amdgcn_global_load_lds((as1cv)(gt + i * 512),
                                             (as3v)(lbase + i * 512), 16, 0, 0);
        }
    };

    issue(0, 0);
    __syncthreads();   // per-wave vmcnt(0) drain before barrier -> tile 0 ready

    for (int t = 0; t < 32; ++t) {
        const int cur = t & 1;
        if (t + 1 < 32) issue(t + 1, 1 - cur);   // prefetch overlaps compute

        const ushort* kt = &ktile[half][cur][0];
        const int slotbase = half * 2048 + t * 64;
        #pragma unroll
        for (int sub = 0; sub < 4; ++sub) {
            f32x4 a0 = {0.f, 0.f, 0.f, 0.f}, a1 = {0.f, 0.f, 0.f, 0.f};
            #pragma unroll
            for (int kc = 0; kc < 4; ++kc) {
                bf16x8 aF = *(const bf16x8*)(kt + (sub * 4 + kc) * 512 + lane * 8);
                a0 = __builtin_amdgcn_mfma_f32_16x16x32_bf16(aF, bF[0][kc], a0, 0, 0, 0);
                a1 = __builtin_amdgcn_mfma_f32_16x16x32_bf16(aF, bF[1][kc], a1, 0, 0, 0);
            }
            float4 lrv = ((const float4*)lr)[(slotbase + sub * 16) / 4 + kseg];
            unsigned invb = 4095u - (unsigned)(slotbase + sub * 16 + kseg * 4);
            ins_packed(R0, pack_score(a0[0] + lrv.x, invb));
            ins_packed(R0, pack_score(a0[1] + lrv.y, invb - 1));
            ins_packed(R0, pack_score(a0[2] + lrv.z, invb - 2));
            ins_packed(R0, pack_score(a0[3] + lrv.w, invb - 3));
            ins_packed(R1, pack_score(a1[0] + lrv.x, invb));
            ins_packed(R1, pack_score(a1[1] + lrv.y, invb - 1));
            ins_packed(R1, pack_score(a1[2] + lrv.z, invb - 2));
            ins_packed(R1, pack_score(a1[3] + lrv.w, invb - 3));
        }
        __syncthreads();   // readers done + my next-tile DMA drained
    }

    merge_out16(R0, kseg, tokbase + m,      half, cand);
    merge_out16(R1, kseg, tokbase + 16 + m, half, cand);
}

// ---------------- kernel 2: exact fp32 rescue + final top-8 + softmax -------
// 1 wave per token (4/block); lane = cand(32) x dim-half(2). Exact fp32 q.k
// on the 32-candidate pool, butterfly arg-max (biased desc, idx asc; twin
// lanes hold duplicates and deactivate together), softmax on raw scores.
__launch_bounds__(256)
__global__ void rescue_kernel(const float* __restrict__ query,
                              const float* __restrict__ keys,
                              const float* __restrict__ lr,
                              const int*   __restrict__ cand,
                              float* __restrict__ wout,
                              int*   __restrict__ idxws) {
    const int tid  = threadIdx.x;
    const int w    = tid >> 6;
    const int lane = tid & 63;
    const int token = blockIdx.x * 4 + w;
    const int c = lane >> 1;    // candidate 0..31
    const int h = lane & 1;     // dim half

    int ci = cand[(size_t)token * 32 + c];
    const float4* q4 = (const float4*)(query + (size_t)token * DIM) + h * 16;
    const float4* k4 = (const float4*)(keys  + (size_t)ci    * DIM) + h * 16;
    float sum = 0.f;
    #pragma unroll
    for (int i = 0; i < 16; ++i) {
        float4 a = q4[i], b = k4[i];
        sum = fmaf(a.x, b.x, sum); sum = fmaf(a.y, b.y, sum);
        sum = fmaf(a.z, b.z, sum); sum = fmaf(a.w, b.w, sum);
    }
    sum += __shfl_xor(sum, 1, 64);   // both twins hold full dot
    float raw = sum;
    float s   = sum + lr[ci];        // biased, exact fp32

    float rsel[8]; int isel[8];
    #pragma unroll
    for (int rnd = 0; rnd < 8; ++rnd) {
        float bv = s; int bi = ci; float br = raw;
        #pragma unroll
        for (int off = 1; off < 64; off <<= 1) {
            float ov = __shfl_xor(bv, off, 64);
            int   oi = __shfl_xor(bi, off, 64);
            float orr = __shfl_xor(br, off, 64);
            if (ov > bv || (ov == bv && oi < bi)) { bv = ov; bi = oi; br = orr; }
        }
        rsel[rnd] = br; isel[rnd] = bi;
        if (s == bv && ci == bi) s = -INFINITY;   // winner (both twins) retires
    }

    if (lane == 0) {
        float mx = -INFINITY;
        #pragma unroll
        for (int k = 0; k < 8; ++k) { rsel[k] *= SCALE; mx = fmaxf(mx, rsel[k]); }
        float e[8]; float ssum = 0.f;
        #pragma unroll
        for (int k = 0; k < 8; ++k) { e[k] = expf(rsel[k] - mx); ssum += e[k]; }
        float inv = 1.0f / ssum;
        #pragma unroll
        for (int k = 0; k < 8; ++k) {
            wout[(size_t)token * 8 + k]  = e[k] * inv;
            idxws[(size_t)token * 8 + k] = isel[k];
        }
    }
}

// ---------------- kernel 3: weighted value gather ----------------
__launch_bounds__(256)
__global__ void gather_kernel(const float* __restrict__ values,
                              const int*   __restrict__ idxws,
                              const float* __restrict__ wout,
                              float* __restrict__ out) {
    const int token = blockIdx.x;
    __shared__ int   sidx[8];
    __shared__ float sw[8];
    if (threadIdx.x < 8) {
        sidx[threadIdx.x] = idxws[(size_t)token * 8 + threadIdx.x];
        sw[threadIdx.x]   = wout[(size_t)token * 8 + threadIdx.x];
    }
    __syncthreads();
    const int h4 = threadIdx.x;
    const float4* V4 = (const float4*)values;
    float4 acc = make_float4(0.f, 0.f, 0.f, 0.f);
    #pragma unroll
    for (int k = 0; k < 8; ++k) {
        float4 v = V4[(size_t)sidx[k] * 256 + h4];
        float  ww = sw[k];
        acc.x = fmaf(ww, v.x, acc.x);
        acc.y = fmaf(ww, v.y, acc.y);
        acc.z = fmaf(ww, v.z, acc.z);
        acc.w = fmaf(ww, v.w, acc.w);
    }
    ((float4*)out)[(size_t)token * 256 + h4] = acc;
}

// ---------------- launch ----------------
extern "C" void kernel_launch(void* const* d_in, const int* in_sizes, int n_in,
                              void* d_out, int out_size, void* d_ws, size_t ws_size,
                              hipStream_t stream) {
    const float* query  = (const float*)d_in[0];
    const float* keys   = (const float*)d_in[1];
    const float* values = (const float*)d_in[2];
    const float* rel    = (const float*)d_in[3];

    float* out  = (float*)d_out;                 // [16384, 1024]
    float* wout = out + (size_t)NTOK * HDIM;     // [16384, 8]

    char* ws = (char*)d_ws;
    float*  lr    = (float*)ws;   ws += 4096 * 4;                    // 16 KB
    ushort* qb    = (ushort*)ws;  ws += (size_t)NTOK * DIM * 2;      // 4 MB
    ushort* kbp   = (ushort*)ws;  ws += (size_t)NSLOTS * DIM * 2;    // 1 MB
    int*    cand  = (int*)ws;     ws += (size_t)NTOK * 32 * 4;       // 2 MB
    int*    idxws = (int*)ws;                                        // 0.5 MB

    int prep_grid = (524288 + 65536 + 4096) / 256;   // = 2320
    hipLaunchKernelGGL(prep_kernel, dim3(prep_grid), dim3(256), 0, stream,
                       query, keys, rel, qb, kbp, lr);
    hipLaunchKernelGGL(route_kernel, dim3(NTOK / 64), dim3(256), 0, stream,
                       qb, kbp, lr, cand);
    hipLaunchKernelGGL(rescue_kernel, dim3(NTOK / 4), dim3(256), 0, stream,
                       query, keys, lr, cand, wout, idxws);
    hipLaunchKernelGGL(gather_kernel, dim3(NTOK), dim3(256), 0, stream,
                       values, idxws, wout, out);
}

// Round 6
// 226.154 us; speedup vs baseline: 16.4332x; 1.2183x over previous
//
#include <hip/hip_runtime.h>
#include <math.h>

#define NSLOTS 4096
#define DIM    128
#define HDIM   1024
#define NTOK   16384   // 4 * 4096
#define SCALE  0.08838834764831845f  // 1/sqrt(128)
#define REPS   1e-10f

typedef __attribute__((ext_vector_type(8))) short bf16x8;
typedef __attribute__((ext_vector_type(4))) float f32x4;

typedef __attribute__((address_space(1))) const void* as1cv;
typedef __attribute__((address_space(3))) void* as3v;

// ---- packed (score | 4095-slot) helpers -----------------------------------
// Low 12 mantissa bits replaced by (4095-slot): float compare = score desc,
// then slot asc. fp32 rescue re-ranks the 16-candidate pool exactly, so only
// pool membership at the noise margin matters (per-quarter top-16 width).
__device__ __forceinline__ float pack_score(float biased, unsigned inv_idx) {
    return __uint_as_float((__float_as_uint(biased) & 0xFFFFF000u) | inv_idx);
}
#define PACK_NEG_INF __uint_as_float(0xFF7FF000u)   // ~ -FLT_MAX, valid finite

// Branchless insert into ascending sorted r[0..7] (r[7]=max), drop min.
// med3(a,x,b) with a<=b == min(max(a,x),b): 8 VALU ops total.
__device__ __forceinline__ void ins_packed(float (&r)[8], float x) {
    #pragma unroll
    for (int i = 0; i < 7; ++i) r[i] = __builtin_amdgcn_fmed3f(r[i], x, r[i + 1]);
    r[7] = fmaxf(r[7], x);
}

// Pop-merge 4 kseg-lanes' sorted top-8 (32 values) -> this quarter's sorted
// top-16 (desc, packed) into LDS. Group = lanes {l, l^16, l^32, l^48}.
__device__ __forceinline__ void merge_out16(float (&r)[8], int kseg, float* outS) {
    float hv = r[7];
    #pragma unroll
    for (int rnd = 0; rnd < 16; ++rnd) {
        float bv = hv;
        bv = fmaxf(bv, __shfl_xor(bv, 16, 64));
        bv = fmaxf(bv, __shfl_xor(bv, 32, 64));
        if ((rnd >> 2) == kseg) outS[rnd] = bv;   // each kseg-lane writes 4
        if (hv == bv) {   // my head won (packed values distinct in group): pop
            #pragma unroll
            for (int m2 = 7; m2 > 0; --m2) r[m2] = r[m2 - 1];
            r[0] = PACK_NEG_INF;
            hv = r[7];
        }
    }
}

// ---------------- kernel 0: prep (bf16 convert + K permute + log-rel) -------
__device__ __forceinline__ ushort f2bf(float f) {   // RNE
    unsigned u = __float_as_uint(f);
    return (ushort)((u + 0x7fffu + ((u >> 16) & 1u)) >> 16);
}
// kbp chunk C (16 B = 8 bf16): C = t16*256 + kc*64 + l
//   t16 = 16-slot tile (0..255), kc = K-chunk (0..3), l = lane
//   source = keys[slot = t16*16 + (l&15)][kc*32 + (l>>4)*8 .. +8)
__global__ void prep_kernel(const float* __restrict__ q, const float* __restrict__ k,
                            const float* __restrict__ rel,
                            ushort* __restrict__ qb, ushort* __restrict__ kbp,
                            float* __restrict__ lr) {
    int gid = blockIdx.x * 256 + threadIdx.x;
    if (gid < 524288) {                       // qb row-major: 2,097,152 floats / 4
        float4 v = ((const float4*)q)[gid];
        ushort4 o; o.x = f2bf(v.x); o.y = f2bf(v.y); o.z = f2bf(v.z); o.w = f2bf(v.w);
        ((ushort4*)qb)[gid] = o;
    } else if (gid < 524288 + 65536) {        // kbp fragment-permuted chunks
        int C = gid - 524288;
        int l = C & 63, kc = (C >> 6) & 3, t16 = C >> 8;
        int slot = t16 * 16 + (l & 15);
        int doff = kc * 32 + (l >> 4) * 8;
        const float4* src = (const float4*)(k + (size_t)slot * DIM + doff);
        float4 v0 = src[0], v1 = src[1];
        union { ushort u[8]; uint4 v; } o;
        o.u[0] = f2bf(v0.x); o.u[1] = f2bf(v0.y); o.u[2] = f2bf(v0.z); o.u[3] = f2bf(v0.w);
        o.u[4] = f2bf(v1.x); o.u[5] = f2bf(v1.y); o.u[6] = f2bf(v1.z); o.u[7] = f2bf(v1.w);
        ((uint4*)kbp)[C] = o.v;
    } else if (gid < 524288 + 65536 + 4096) {
        int g = gid - 524288 - 65536;
        lr[g] = logf(rel[g] + REPS);
    }
}

// ---------------- kernel 1: MFMA router + packed top-8 ----------------------
// Grid 1024 x 256 thr (4 waves). Block = 16 tokens, all 4096 slots; wave w =
// slot quarter (1024 slots = 64 tiles of 16). A = keys (DMA double-buffered
// LDS, 4 KB tiles), B = queries (stationary VGPRs, 16 tokens). D (16x16x32):
// row = slot-in-tile = kseg*4+reg, col = token = lane&15. Per-lane top-8 of
// its 256-slot partition; 4-lane merge -> quarter top-16; in-block 4-way
// merge -> global approx top-16 -> cand. One barrier per tile.
// LDS 36 KB -> 4 blocks/CU = 16 waves/CU.
__launch_bounds__(256, 4)
__global__ void route_kernel(const ushort* __restrict__ qb,
                             const ushort* __restrict__ kbp,
                             const float*  __restrict__ lr,
                             int* __restrict__ cand) {
    __shared__ ushort ktile[4][2][4 * 512];   // [quarter][buf][frag*512] = 32 KB
    __shared__ float  qS[16][4][16];          // per-token per-quarter sorted top-16
    const int tid  = threadIdx.x;
    const int lane = tid & 63;
    const int q    = tid >> 6;     // slot quarter = wave id
    const int m    = lane & 15;    // token col
    const int kseg = lane >> 4;
    const int tokbase = blockIdx.x * 16;

    // stationary B-frags (queries): lane (n=m, kseg) needs Q[tok][kc*32+kseg*8..+8)
    bf16x8 bF[4];
    const ushort* qrow = qb + (size_t)(tokbase + m) * DIM + kseg * 8;
    #pragma unroll
    for (int kc = 0; kc < 4; ++kc)
        bF[kc] = *(const bf16x8*)(qrow + kc * 32);

    float R[8];
    #pragma unroll
    for (int i = 0; i < 8; ++i) R[i] = PACK_NEG_INF;

    // DMA one 16-slot tile (4 KB = 4 frag-chunks x 64 lanes x 16 B)
    auto issue = [&](int t, int buf) {
        const ushort* gt = kbp + ((size_t)((q * 64 + t) * 256 + lane)) * 8;
        ushort* lb = &ktile[q][buf][0];
        #pragma unroll
        for (int i = 0; i < 4; ++i) {
            __builtin_amdgcn_global_load_lds((as1cv)(gt + i * 512),
                                             (as3v)(lb + i * 512 + lane * 8), 16, 0, 0);
        }
    };

    issue(0, 0);
    __syncthreads();   // barrier's vmcnt(0) drain -> tile 0 resident

    for (int t = 0; t < 64; ++t) {
        const int cur = t & 1;
        if (t < 63) issue(t + 1, 1 - cur);   // prefetch into other buffer

        const ushort* kt = &ktile[q][cur][0];
        f32x4 acc = {0.f, 0.f, 0.f, 0.f};
        #pragma unroll
        for (int kc = 0; kc < 4; ++kc) {
            bf16x8 aF = *(const bf16x8*)(kt + kc * 512 + lane * 8);
            acc = __builtin_amdgcn_mfma_f32_16x16x32_bf16(aF, bF[kc], acc, 0, 0, 0);
        }
        const int base = q * 1024 + t * 16;
        float4 lrv = ((const float4*)lr)[(base >> 2) + kseg];
        unsigned invb = 4095u - (unsigned)(base + kseg * 4);
        ins_packed(R, pack_score(acc[0] + lrv.x, invb));
        ins_packed(R, pack_score(acc[1] + lrv.y, invb - 1));
        ins_packed(R, pack_score(acc[2] + lrv.z, invb - 2));
        ins_packed(R, pack_score(acc[3] + lrv.w, invb - 3));
        __syncthreads();   // readers done with cur + prefetch DMA drained
    }

    merge_out16(R, kseg, &qS[m][q][0]);
    __syncthreads();

    // 4-way merge of the quarters' sorted-desc lists -> global approx top-16
    if (tid < 16) {
        const int token = tokbase + tid;
        int p[4] = {0, 0, 0, 0};
        #pragma unroll
        for (int c = 0; c < 16; ++c) {
            float bv = -INFINITY; int bq = 0;
            #pragma unroll
            for (int j = 0; j < 4; ++j) {
                float v = (p[j] < 16) ? qS[tid][j][p[j]] : -INFINITY;
                if (v > bv) { bv = v; bq = j; }
            }
            cand[(size_t)token * 16 + c] = 4095 - (int)(__float_as_uint(bv) & 0xFFFu);
            ++p[bq];
        }
    }
}

// ---------------- kernel 2: fused fp32 rescue + softmax + V gather ----------
// 1 wave per token (4/block); lane = cand(16) x dim-quarter(4). Exact fp32
// q.k on the 16-candidate pool, butterfly arg-max (biased desc, idx asc;
// 4 twin lanes per candidate retire together), softmax on raw scores, then
// the wave gathers/accumulates the 8 weighted V rows (weights in registers).
__launch_bounds__(256)
__global__ void rescue_gather_kernel(const float* __restrict__ query,
                                     const float* __restrict__ keys,
                                     const float* __restrict__ lr,
                                     const int*   __restrict__ cand,
                                     const float* __restrict__ values,
                                     float* __restrict__ out,
                                     float* __restrict__ wout) {
    const int tid  = threadIdx.x;
    const int w    = tid >> 6;
    const int lane = tid & 63;
    const int token = blockIdx.x * 4 + w;
    const int c  = lane >> 2;    // candidate 0..15
    const int qp = lane & 3;     // dim quarter (32 floats)

    int ci = cand[(size_t)token * 16 + c];
    const float4* q4 = (const float4*)(query + (size_t)token * DIM) + qp * 8;
    const float4* k4 = (const float4*)(keys  + (size_t)ci    * DIM) + qp * 8;
    float sum = 0.f;
    #pragma unroll
    for (int i = 0; i < 8; ++i) {
        float4 a = q4[i], b = k4[i];
        sum = fmaf(a.x, b.x, sum); sum = fmaf(a.y, b.y, sum);
        sum = fmaf(a.z, b.z, sum); sum = fmaf(a.w, b.w, sum);
    }
    sum += __shfl_xor(sum, 1, 4);
    sum += __shfl_xor(sum, 2, 4);    // all 4 twins hold the full dot
    float raw = sum;
    float s   = sum + lr[ci];        // biased, exact fp32

    float rsel[8]; int isel[8];
    #pragma unroll
    for (int rnd = 0; rnd < 8; ++rnd) {
        float bv = s; int bi = ci; float br = raw;
        #pragma unroll
        for (int off = 4; off < 64; off <<= 1) {   // compare across candidates only
            float ov  = __shfl_xor(bv, off, 64);
            int   oi  = __shfl_xor(bi, off, 64);
            float orr = __shfl_xor(br, off, 64);
            if (ov > bv || (ov == bv && oi < bi)) { bv = ov; bi = oi; br = orr; }
        }
        rsel[rnd] = br; isel[rnd] = bi;
        if (s == bv && ci == bi) s = -INFINITY;   // winner (all 4 twins) retires
    }

    // softmax on raw*SCALE — computed redundantly in every lane (weights
    // needed in registers for the gather)
    float mx = -INFINITY;
    #pragma unroll
    for (int k = 0; k < 8; ++k) { rsel[k] *= SCALE; mx = fmaxf(mx, rsel[k]); }
    float e[8]; float ssum = 0.f;
    #pragma unroll
    for (int k = 0; k < 8; ++k) { e[k] = expf(rsel[k] - mx); ssum += e[k]; }
    float inv = 1.0f / ssum;
    float wk[8];
    #pragma unroll
    for (int k = 0; k < 8; ++k) wk[k] = e[k] * inv;

    if (lane == 0) {
        #pragma unroll
        for (int k = 0; k < 8; ++k) wout[(size_t)token * 8 + k] = wk[k];
    }

    // fused gather: 1024 dims = 4 passes x 64 lanes x float4
    const float4* V4 = (const float4*)values;
    float4 o0 = {0,0,0,0}, o1 = {0,0,0,0}, o2 = {0,0,0,0}, o3 = {0,0,0,0};
    #pragma unroll
    for (int k = 0; k < 8; ++k) {
        const float4* vr = V4 + (size_t)isel[k] * 256;
        float wkk = wk[k];
        float4 v;
        v = vr[lane];       o0.x = fmaf(wkk, v.x, o0.x); o0.y = fmaf(wkk, v.y, o0.y);
                            o0.z = fmaf(wkk, v.z, o0.z); o0.w = fmaf(wkk, v.w, o0.w);
        v = vr[lane + 64];  o1.x = fmaf(wkk, v.x, o1.x); o1.y = fmaf(wkk, v.y, o1.y);
                            o1.z = fmaf(wkk, v.z, o1.z); o1.w = fmaf(wkk, v.w, o1.w);
        v = vr[lane + 128]; o2.x = fmaf(wkk, v.x, o2.x); o2.y = fmaf(wkk, v.y, o2.y);
                            o2.z = fmaf(wkk, v.z, o2.z); o2.w = fmaf(wkk, v.w, o2.w);
        v = vr[lane + 192]; o3.x = fmaf(wkk, v.x, o3.x); o3.y = fmaf(wkk, v.y, o3.y);
                            o3.z = fmaf(wkk, v.z, o3.z); o3.w = fmaf(wkk, v.w, o3.w);
    }
    float4* orow = (float4*)(out + (size_t)token * HDIM);
    orow[lane]       = o0;
    orow[lane + 64]  = o1;
    orow[lane + 128] = o2;
    orow[lane + 192] = o3;
}

// ---------------- launch ----------------
extern "C" void kernel_launch(void* const* d_in, const int* in_sizes, int n_in,
                              void* d_out, int out_size, void* d_ws, size_t ws_size,
                              hipStream_t stream) {
    const float* query  = (const float*)d_in[0];
    const float* keys   = (const float*)d_in[1];
    const float* values = (const float*)d_in[2];
    const float* rel    = (const float*)d_in[3];

    float* out  = (float*)d_out;                 // [16384, 1024]
    float* wout = out + (size_t)NTOK * HDIM;     // [16384, 8]

    char* ws = (char*)d_ws;
    float*  lr   = (float*)ws;   ws += 4096 * 4;                    // 16 KB
    ushort* qb   = (ushort*)ws;  ws += (size_t)NTOK * DIM * 2;      // 4 MB
    ushort* kbp  = (ushort*)ws;  ws += (size_t)NSLOTS * DIM * 2;    // 1 MB
    int*    cand = (int*)ws;                                        // 1 MB

    int prep_grid = (524288 + 65536 + 4096) / 256;   // = 2320
    hipLaunchKernelGGL(prep_kernel, dim3(prep_grid), dim3(256), 0, stream,
                       query, keys, rel, qb, kbp, lr);
    hipLaunchKernelGGL(route_kernel, dim3(NTOK / 16), dim3(256), 0, stream,
                       qb, kbp, lr, cand);
    hipLaunchKernelGGL(rescue_gather_kernel, dim3(NTOK / 4), dim3(256), 0, stream,
                       query, keys, lr, cand, values, out, wout);
}